// Round 13
// baseline (166.274 us; speedup 1.0000x reference)
//
#include <hip/hip_runtime.h>

#define B_ 8
#define M_ 4096
#define E_ 1024
#define D_ 256
#define C_ 16

typedef unsigned short u16;
typedef unsigned int u32;
typedef float fv4 __attribute__((ext_vector_type(4)));
typedef short bh8 __attribute__((ext_vector_type(8)));

__device__ __forceinline__ float b2f(u16 v) { return __uint_as_float(((unsigned)v) << 16); }
__device__ __forceinline__ u16 f2b(float f) {
  unsigned u = __float_as_uint(f);
  return (u16)((u + 0x7FFFu + ((u >> 16) & 1u)) >> 16);
}
// packs lo -> low 16 bits, hi -> high 16 bits, RNE
__device__ __forceinline__ u32 cvtpk(float lo, float hi) {
  u32 r;
  asm("v_cvt_pk_bf16_f32 %0, %1, %2" : "=v"(r) : "v"(lo), "v"(hi));
  return r;
}

// ---------- convert two f32 arrays to bf16 (Wa, Wp) ----------
__global__ __launch_bounds__(256) void k_cvt2(const float* __restrict__ a, u16* __restrict__ da,
                                              const float* __restrict__ b, u16* __restrict__ db, int n) {
  int i = (blockIdx.x * 256 + threadIdx.x) * 4;
  if (i >= n) return;
  float4 v = *reinterpret_cast<const float4*>(a + i);
  float4 u = *reinterpret_cast<const float4*>(b + i);
  da[i] = f2b(v.x); da[i + 1] = f2b(v.y); da[i + 2] = f2b(v.z); da[i + 3] = f2b(v.w);
  db[i] = f2b(u.x); db[i + 1] = f2b(u.y); db[i + 2] = f2b(u.z); db[i + 3] = f2b(u.w);
}

// ---------- split-K partial GEMM: P[kc] = inc^T @ nf over 512-m chunk ----------
// BM=128(e) x BN=256(full d) x BK=32, split-K=8. Grid 512 (b=f&7, eb, kc).
// 512 thr = 8 waves (2e x 4d of 64x64). LDS 60KB/block -> 2 blocks/CU = 16 waves/CU.
// Padded rows [.][40] (80B stride): 2-way bank aliasing (free), no swizzle needed.
__global__ __launch_bounds__(512, 4) void k_gemm0(const float* __restrict__ inc,
                                                  const float* __restrict__ nf,
                                                  float* __restrict__ P) {
  __shared__ u16 As[2][128][40];
  __shared__ u16 Bs[2][256][40];
  int f = blockIdx.x;
  int b = f & 7, s = f >> 3;
  int eb = s & 7, kc = s >> 3;  // kc 0..7, 512 m each
  int r0 = eb * 128;
  const float* Ab = inc + (long)b * M_ * E_ + (long)kc * 512 * E_;  // [m][e]
  const float* Bb = nf + (long)b * M_ * D_ + (long)kc * 512 * D_;   // [m][d]
  int t = threadIdx.x, l = t & 63, w = t >> 6;
  int l15 = l & 15, lg = l >> 4;
  int we = (w >> 2) * 64, wd = (w & 3) * 64;

  // staging: A 128e x 32m (2 fv4/thread), B 256d x 32m (4 fv4/thread)
  int mA = t >> 5;          // 0..15 -> m rows mA*2, mA*2+1
  int ae = (t & 31) * 4;    // e offset 0..124
  int mB = t >> 6;          // 0..7 -> m rows mB*4..+3
  int bd = (t & 63) * 4;    // d offset 0..252

  fv4 acc[4][4] = {};
  fv4 pa[2], pb[4];

  auto LOAD = [&](int k0) {
    pa[0] = *reinterpret_cast<const fv4*>(Ab + (long)(k0 + mA * 2) * E_ + r0 + ae);
    pa[1] = *reinterpret_cast<const fv4*>(Ab + (long)(k0 + mA * 2 + 1) * E_ + r0 + ae);
#pragma unroll
    for (int r = 0; r < 4; ++r)
      pb[r] = *reinterpret_cast<const fv4*>(Bb + (long)(k0 + mB * 4 + r) * D_ + bd);
  };
  auto WRITE = [&](int buf) {
#pragma unroll
    for (int j = 0; j < 4; ++j) {
      int e = ae + j;
      *reinterpret_cast<u32*>(&As[buf][e][mA * 2]) = cvtpk(pa[0][j], pa[1][j]);
    }
#pragma unroll
    for (int j = 0; j < 4; ++j) {
      int d = bd + j;
      uint2 vb;
      vb.x = cvtpk(pb[0][j], pb[1][j]);
      vb.y = cvtpk(pb[2][j], pb[3][j]);
      *reinterpret_cast<uint2*>(&Bs[buf][d][mB * 4]) = vb;
    }
  };
  auto COMPUTE = [&](int buf) {
    bh8 af[4];
#pragma unroll
    for (int i = 0; i < 4; ++i)
      af[i] = *reinterpret_cast<const bh8*>(&As[buf][we + i * 16 + l15][lg * 8]);
#pragma unroll
    for (int jj = 0; jj < 4; ++jj) {
      bh8 bf = *reinterpret_cast<const bh8*>(&Bs[buf][wd + jj * 16 + l15][lg * 8]);
#pragma unroll
      for (int i = 0; i < 4; ++i)
        acc[i][jj] = __builtin_amdgcn_mfma_f32_16x16x32_bf16(af[i], bf, acc[i][jj], 0, 0, 0);
    }
  };

  LOAD(0);
  WRITE(0);
  __syncthreads();
  const int NIT = 16;  // 512 / 32
  for (int kt = 0; kt < NIT; ++kt) {
    if (kt < NIT - 1) LOAD((kt + 1) * 32);
    COMPUTE(kt & 1);
    if (kt < NIT - 1) {
      WRITE((kt + 1) & 1);
      __syncthreads();
    }
  }

  float* Pp = P + ((long)(kc * B_ + b) * E_ + r0) * D_;
#pragma unroll
  for (int i = 0; i < 4; ++i)
#pragma unroll
    for (int jj = 0; jj < 4; ++jj)
#pragma unroll
      for (int q = 0; q < 4; ++q) {
        int row = we + i * 16 + lg * 4 + q;
        int col = wd + jj * 16 + l15;
        Pp[(long)row * D_ + col] = acc[i][jj][q];
      }
}

// ---------- reduce 8 split-K partials -> G bf16 ----------
__global__ __launch_bounds__(256) void k_red(const float* __restrict__ P, u16* __restrict__ G) {
  const long CS = (long)B_ * E_ * D_;
  long i = ((long)blockIdx.x * 256 + threadIdx.x) * 4;
  fv4 s0 = *reinterpret_cast<const fv4*>(P + i);
  fv4 s1 = *reinterpret_cast<const fv4*>(P + CS + i);
  fv4 s2 = *reinterpret_cast<const fv4*>(P + 2 * CS + i);
  fv4 s3 = *reinterpret_cast<const fv4*>(P + 3 * CS + i);
  fv4 s4 = *reinterpret_cast<const fv4*>(P + 4 * CS + i);
  fv4 s5 = *reinterpret_cast<const fv4*>(P + 5 * CS + i);
  fv4 s6 = *reinterpret_cast<const fv4*>(P + 6 * CS + i);
  fv4 s7 = *reinterpret_cast<const fv4*>(P + 7 * CS + i);
  fv4 sum = ((s0 + s1) + (s2 + s3)) + ((s4 + s5) + (s6 + s7));
  uint2 o;
  o.x = cvtpk(sum[0], sum[1]);
  o.y = cvtpk(sum[2], sum[3]);
  *reinterpret_cast<uint2*>(G + i) = o;
}

// ---------- small-K GEMM: out = A' @ W^T, K=256 in 4 chunks of 64, depth-2 prefetch ----------
// MODE 2: A'=G bf16, write S f32 + per-block column softmax partial stats (seg y of 16).
// MODE 1: A'=H=G*exp(S-mx)*sv fused in staging; ef = alpha*edge+(1-alpha)*C; fused z-partials.
template <int MODE>
__global__ __launch_bounds__(256, 2) void k_gemmS(
    const u16* __restrict__ A, const u16* __restrict__ Bt,
    const float* __restrict__ Sin, const float* __restrict__ mx, const float* __restrict__ sv,
    float* __restrict__ Sout, float* __restrict__ mxp, float* __restrict__ smp,
    const float* __restrict__ edge, const float* __restrict__ alphap,
    float* __restrict__ outEF, const float* __restrict__ attw, float* __restrict__ zp) {
  __shared__ u16 As[2][64][72];
  __shared__ u16 Bs[2][64][72];
  __shared__ float sM[2][64], sS[2][64];
  __shared__ float sMx[D_], sSv[D_];
  int f = blockIdx.x;
  int b = f & 7, s = f >> 3;
  int x = s & 3, y = s >> 2;
  int r0 = y * 64, c0 = x * 64;
  const u16* Ab = A + (long)b * E_ * D_;
  int t = threadIdx.x, l = t & 63, w = t >> 6;
  int wr = w >> 1, wc = w & 1;
  int l15 = l & 15, lg = l >> 4;
  int rA = t >> 2, kA = (t & 3) * 16;

  if (MODE == 1 && t < 64) {
    *reinterpret_cast<fv4*>(&sMx[t * 4]) = *reinterpret_cast<const fv4*>(mx + b * D_ + t * 4);
    *reinterpret_cast<fv4*>(&sSv[t * 4]) = *reinterpret_cast<const fv4*>(sv + b * D_ + t * 4);
  }
  __syncthreads();  // sMx/sSv visible to ALL threads before any WRITE uses them

  fv4 acc[2][2] = {};
  bh8 ga0[2], gb0[2], ga1[2], gb1[2];
  fv4 sa0[4], sa1[4];

  auto LOAD = [&](int k0, bh8 (&ga)[2], bh8 (&gb)[2], fv4 (&sa)[4]) {
    const u16* ap = Ab + (long)(r0 + rA) * D_ + k0 + kA;
    const u16* bp = Bt + (long)(c0 + rA) * D_ + k0 + kA;
    ga[0] = *reinterpret_cast<const bh8*>(ap);
    ga[1] = *reinterpret_cast<const bh8*>(ap + 8);
    gb[0] = *reinterpret_cast<const bh8*>(bp);
    gb[1] = *reinterpret_cast<const bh8*>(bp + 8);
    if (MODE == 1) {
      const float* sp2 = Sin + ((long)b * E_ + r0 + rA) * D_ + k0 + kA;
#pragma unroll
      for (int i = 0; i < 4; ++i) sa[i] = *reinterpret_cast<const fv4*>(sp2 + i * 4);
    }
  };
  auto WRITE = [&](const bh8 (&ga)[2], const bh8 (&gb)[2], const fv4 (&sa)[4], int buf, int k0) {
    if (MODE == 2) {
      *reinterpret_cast<bh8*>(&As[buf][rA][kA]) = ga[0];
      *reinterpret_cast<bh8*>(&As[buf][rA][kA + 8]) = ga[1];
    } else {
#pragma unroll
      for (int h = 0; h < 2; ++h) {
        fv4 mA = *reinterpret_cast<const fv4*>(&sMx[k0 + kA + h * 8]);
        fv4 mB = *reinterpret_cast<const fv4*>(&sMx[k0 + kA + h * 8 + 4]);
        fv4 vA = *reinterpret_cast<const fv4*>(&sSv[k0 + kA + h * 8]);
        fv4 vB = *reinterpret_cast<const fv4*>(&sSv[k0 + kA + h * 8 + 4]);
        float hf[8];
#pragma unroll
        for (int j = 0; j < 4; ++j) {
          hf[j]     = b2f((u16)ga[h][j])     * __expf(sa[h * 2][j]     - mA[j]) * vA[j];
          hf[4 + j] = b2f((u16)ga[h][j + 4]) * __expf(sa[h * 2 + 1][j] - mB[j]) * vB[j];
        }
        union { u32 w4[4]; bh8 v; } hp;
        hp.w4[0] = cvtpk(hf[0], hf[1]);
        hp.w4[1] = cvtpk(hf[2], hf[3]);
        hp.w4[2] = cvtpk(hf[4], hf[5]);
        hp.w4[3] = cvtpk(hf[6], hf[7]);
        *reinterpret_cast<bh8*>(&As[buf][rA][kA + h * 8]) = hp.v;
      }
    }
    *reinterpret_cast<bh8*>(&Bs[buf][rA][kA]) = gb[0];
    *reinterpret_cast<bh8*>(&Bs[buf][rA][kA + 8]) = gb[1];
  };
  auto COMPUTE = [&](int buf) {
#pragma unroll
    for (int kk = 0; kk < 2; ++kk) {
      bh8 af[2], bf[2];
#pragma unroll
      for (int i = 0; i < 2; ++i)
        af[i] = *reinterpret_cast<const bh8*>(&As[buf][wr * 32 + i * 16 + l15][kk * 32 + lg * 8]);
#pragma unroll
      for (int j = 0; j < 2; ++j)
        bf[j] = *reinterpret_cast<const bh8*>(&Bs[buf][wc * 32 + j * 16 + l15][kk * 32 + lg * 8]);
#pragma unroll
      for (int i = 0; i < 2; ++i)
#pragma unroll
        for (int j = 0; j < 2; ++j)
          acc[i][j] = __builtin_amdgcn_mfma_f32_16x16x32_bf16(af[i], bf[j], acc[i][j], 0, 0, 0);
    }
  };

  const int NT = D_ / 64;
  LOAD(0, ga0, gb0, sa0);
  LOAD(64, ga1, gb1, sa1);
  WRITE(ga0, gb0, sa0, 0, 0);
  __syncthreads();
  for (int kt = 0; kt < NT; kt += 2) {
    if (kt + 2 < NT) LOAD((kt + 2) * 64, ga0, gb0, sa0);
    COMPUTE(0);
    WRITE(ga1, gb1, sa1, 1, (kt + 1) * 64);
    __syncthreads();
    if (kt + 3 < NT) LOAD((kt + 3) * 64, ga1, gb1, sa1);
    COMPUTE(1);
    if (kt + 2 < NT) WRITE(ga0, gb0, sa0, 0, (kt + 2) * 64);
    __syncthreads();
  }

  if (MODE == 2) {
#pragma unroll
    for (int i = 0; i < 2; ++i)
#pragma unroll
      for (int j = 0; j < 2; ++j)
#pragma unroll
        for (int q = 0; q < 4; ++q) {
          int row = r0 + wr * 32 + i * 16 + lg * 4 + q;
          int col = c0 + wc * 32 + j * 16 + l15;
          Sout[((long)b * E_ + row) * D_ + col] = acc[i][j][q];
        }
#pragma unroll
    for (int j = 0; j < 2; ++j) {
      float m = -3.0e38f;
#pragma unroll
      for (int i = 0; i < 2; ++i)
#pragma unroll
        for (int q = 0; q < 4; ++q) m = fmaxf(m, acc[i][j][q]);
      m = fmaxf(m, __shfl_xor(m, 16));
      m = fmaxf(m, __shfl_xor(m, 32));
      float ssum = 0.f;
#pragma unroll
      for (int i = 0; i < 2; ++i)
#pragma unroll
        for (int q = 0; q < 4; ++q) ssum += __expf(acc[i][j][q] - m);
      ssum += __shfl_xor(ssum, 16);
      ssum += __shfl_xor(ssum, 32);
      if (lg == 0) {
        sM[wr][wc * 32 + j * 16 + l15] = m;
        sS[wr][wc * 32 + j * 16 + l15] = ssum;
      }
    }
    __syncthreads();
    if (t < 64) {
      float m0 = sM[0][t], m1 = sM[1][t];
      float M = fmaxf(m0, m1);
      float ss = sS[0][t] * __expf(m0 - M) + sS[1][t] * __expf(m1 - M);
      int idx = (b * 16 + y) * D_ + c0 + t;
      mxp[idx] = M;
      smp[idx] = ss;
    }
  } else {
    float al = *alphap, oneal = 1.0f - al;
    float aw0 = attw[c0 + wc * 32 + l15];
    float aw1 = attw[c0 + wc * 32 + 16 + l15];
#pragma unroll
    for (int i = 0; i < 2; ++i)
#pragma unroll
      for (int q = 0; q < 4; ++q) {
        int row = r0 + wr * 32 + i * 16 + lg * 4 + q;
        long idx0 = ((long)b * E_ + row) * D_ + c0 + wc * 32 + l15;
        long idx1 = idx0 + 16;
        float ef0 = al * edge[idx0] + oneal * acc[i][0][q];
        float ef1 = al * edge[idx1] + oneal * acc[i][1][q];
        outEF[idx0] = ef0;
        outEF[idx1] = ef1;
        float zv = ef0 * aw0 + ef1 * aw1;
        zv += __shfl_xor(zv, 1);
        zv += __shfl_xor(zv, 2);
        zv += __shfl_xor(zv, 4);
        zv += __shfl_xor(zv, 8);
        if (l15 == 0) zp[((long)(x * 2 + wc) * B_ + b) * E_ + row] = zv;
      }
  }
}

// ---------- combine 16 row-segments of column stats; sv = 1/sum ----------
__global__ __launch_bounds__(256) void k_cstats2(const float* __restrict__ mxp, const float* __restrict__ smp,
                                                 float* __restrict__ mx, float* __restrict__ sv) {
  int i = blockIdx.x * 256 + threadIdx.x;
  int b = i >> 8, d = i & 255;
  float M = -3.0e38f;
#pragma unroll
  for (int s = 0; s < 16; ++s) M = fmaxf(M, mxp[(b * 16 + s) * D_ + d]);
  float S = 0.f;
#pragma unroll
  for (int s = 0; s < 16; ++s) S += smp[(b * 16 + s) * D_ + d] * __expf(mxp[(b * 16 + s) * D_ + d] - M);
  mx[i] = M;
  sv[i] = 1.0f / S;
}

// ---------- softmax over e of z (= sum of 8 zp slices) -> az ----------
__global__ __launch_bounds__(256) void k_zsm(const float* __restrict__ zp, float* __restrict__ az) {
  int b = blockIdx.x, t = threadIdx.x;
  __shared__ float wred[4];
  fv4 v = {};
#pragma unroll
  for (int s = 0; s < 8; ++s)
    v += *reinterpret_cast<const fv4*>(zp + ((long)s * B_ + b) * E_ + t * 4);
  float m = fmaxf(fmaxf(v[0], v[1]), fmaxf(v[2], v[3]));
#pragma unroll
  for (int off = 32; off; off >>= 1) m = fmaxf(m, __shfl_xor(m, off));
  if ((t & 63) == 0) wred[t >> 6] = m;
  __syncthreads();
  m = fmaxf(fmaxf(wred[0], wred[1]), fmaxf(wred[2], wred[3]));
  float e0 = __expf(v[0] - m), e1 = __expf(v[1] - m), e2 = __expf(v[2] - m), e3 = __expf(v[3] - m);
  float ssum = e0 + e1 + e2 + e3;
#pragma unroll
  for (int off = 32; off; off >>= 1) ssum += __shfl_xor(ssum, off);
  __syncthreads();
  if ((t & 63) == 0) wred[t >> 6] = ssum;
  __syncthreads();
  ssum = wred[0] + wred[1] + wred[2] + wred[3];
  float inv = 1.0f / ssum;
  fv4 o;
  o[0] = e0 * inv; o[1] = e1 * inv; o[2] = e2 * inv; o[3] = e3 * inv;
  *reinterpret_cast<fv4*>(az + b * E_ + t * 4) = o;
}

// ---------- pooled[b][d] = sum_e az[b][e] * ef[b][e][d] ----------
__global__ __launch_bounds__(256) void k_pooled(const float* __restrict__ ef, const float* __restrict__ az,
                                                float* __restrict__ pooled) {
  int b = blockIdx.y;
  int d = blockIdx.x * 64 + (threadIdx.x & 63);
  int g = threadIdx.x >> 6;
  float a = 0.f;
  for (int e = g; e < E_; e += 4)
    a += az[b * E_ + e] * ef[((long)b * E_ + e) * D_ + d];
  __shared__ float ps[4][64];
  ps[g][threadIdx.x & 63] = a;
  __syncthreads();
  if (threadIdx.x < 64)
    pooled[b * D_ + blockIdx.x * 64 + threadIdx.x] =
        ps[0][threadIdx.x] + ps[1][threadIdx.x] + ps[2][threadIdx.x] + ps[3][threadIdx.x];
}

// ---------- out = pooled@proj^T + b ; logits = out@fc^T + fcb ----------
__global__ __launch_bounds__(256) void k_out(const float* __restrict__ pooled,
                                             const float* __restrict__ projw, const float* __restrict__ projb,
                                             const float* __restrict__ fcw, const float* __restrict__ fcb,
                                             float* __restrict__ outp) {
  int b = blockIdx.x, t = threadIdx.x;
  __shared__ float pl[D_], ov[D_];
  pl[t] = pooled[b * D_ + t];
  __syncthreads();
  float o = projb[t];
  for (int d = 0; d < D_; ++d) o += projw[t * D_ + d] * pl[d];
  ov[t] = o;
  __syncthreads();
  if (t < C_) {
    float lg = fcb[t];
    for (int d = 0; d < D_; ++d) lg += fcw[t * D_ + d] * ov[d];
    outp[b * C_ + t] = lg;
  }
}

extern "C" void kernel_launch(void* const* d_in, const int* in_sizes, int n_in,
                              void* d_out, int out_size, void* d_ws, size_t ws_size,
                              hipStream_t stream) {
  const float* node  = (const float*)d_in[0];
  const float* edge  = (const float*)d_in[1];
  const float* inc   = (const float*)d_in[2];
  const float* Wa    = (const float*)d_in[3];
  const float* Wp    = (const float*)d_in[4];
  const float* alpha = (const float*)d_in[5];
  const float* attw  = (const float*)d_in[6];
  const float* projw = (const float*)d_in[7];
  const float* projb = (const float*)d_in[8];
  const float* fcw   = (const float*)d_in[9];
  const float* fcb   = (const float*)d_in[10];
  float* outp = (float*)d_out;

  char* wsp = (char*)d_ws;
  size_t off = 0;
  auto alloc = [&](size_t bytes) {
    char* p = wsp + off;
    off += (bytes + 255) & ~(size_t)255;
    return (void*)p;
  };
  // P (8 x 8.4MB) dead after k_red; S and ef alias the region.
  float* P  = (float*)alloc((size_t)8 * B_ * E_ * D_ * 4);
  float* S  = P;                                  // written after k_red (P dead)
  float* ef = P + (size_t)2 * B_ * E_ * D_;       // written while S (lower region) is read
  u16* Wab  = (u16*)alloc((size_t)D_ * D_ * 2);
  u16* Wpb  = (u16*)alloc((size_t)D_ * D_ * 2);
  u16* G    = (u16*)alloc((size_t)B_ * E_ * D_ * 2);
  float* mxp = (float*)alloc((size_t)B_ * 16 * D_ * 4);
  float* smp = (float*)alloc((size_t)B_ * 16 * D_ * 4);
  float* mx  = (float*)alloc((size_t)B_ * D_ * 4);
  float* sv  = (float*)alloc((size_t)B_ * D_ * 4);
  float* zp  = (float*)alloc((size_t)8 * B_ * E_ * 4);
  float* az  = (float*)alloc((size_t)B_ * E_ * 4);
  float* pooled = (float*)alloc((size_t)B_ * D_ * 4);

  // 1. convert Wa, Wp to bf16
  k_cvt2<<<dim3(D_ * D_ / 1024), 256, 0, stream>>>(Wa, Wab, Wp, Wpb, D_ * D_);
  // 2. split-K partials P[kc] = inc^T @ nf (BK=32, 16 waves/CU)
  k_gemm0<<<dim3(512), 512, 0, stream>>>(inc, node, P);
  // 3. reduce 8 partials -> G bf16
  k_red<<<dim3((B_ * E_ * D_) / 1024), 256, 0, stream>>>(P, G);
  // 4. S = G @ Wa^T (f32) + partial column softmax stats (16 segs)
  k_gemmS<2><<<dim3(512), 256, 0, stream>>>(G, Wab, nullptr, nullptr, nullptr,
                                            S, mxp, smp, nullptr, nullptr, nullptr, nullptr, nullptr);
  // 5. combine stats -> mx, sv(=1/sum)
  k_cstats2<<<dim3(B_ * D_ / 256), 256, 0, stream>>>(mxp, smp, mx, sv);
  // 6. ef = alpha*edge + (1-alpha)*((G*softmax) @ Wp^T); fused z-partials -> zp
  k_gemmS<1><<<dim3(512), 256, 0, stream>>>(G, Wpb, S, mx, sv,
                                            nullptr, nullptr, nullptr, edge, alpha, ef, attw, zp);
  // 7-9. edge softmax + pooling + final projections
  k_zsm<<<dim3(B_), 256, 0, stream>>>(zp, az);
  k_pooled<<<dim3(D_ / 64, B_), 256, 0, stream>>>(ef, az, pooled);
  k_out<<<dim3(B_), 256, 0, stream>>>(pooled, projw, projb, fcw, fcb, outp);
}

// Round 14
// 154.769 us; speedup vs baseline: 1.0743x; 1.0743x over previous
//
#include <hip/hip_runtime.h>

#define B_ 8
#define M_ 4096
#define E_ 1024
#define D_ 256
#define C_ 16

typedef unsigned short u16;
typedef unsigned int u32;
typedef float fv4 __attribute__((ext_vector_type(4)));
typedef short bh8 __attribute__((ext_vector_type(8)));

__device__ __forceinline__ float b2f(u16 v) { return __uint_as_float(((unsigned)v) << 16); }
__device__ __forceinline__ u16 f2b(float f) {
  unsigned u = __float_as_uint(f);
  return (u16)((u + 0x7FFFu + ((u >> 16) & 1u)) >> 16);
}
// packs lo -> low 16 bits, hi -> high 16 bits, RNE
__device__ __forceinline__ u32 cvtpk(float lo, float hi) {
  u32 r;
  asm("v_cvt_pk_bf16_f32 %0, %1, %2" : "=v"(r) : "v"(lo), "v"(hi));
  return r;
}
// per-row granule swizzle (16B granules, 8 per 64-u16 row segment)
__device__ __forceinline__ int xf(int r) { return ((r >> 2) ^ (r >> 5)) & 7; }

// ---------- split-K partial GEMM: P[kc] = inc^T @ nf over m-chunk (r11 verbatim, 77us) ----------
// BM=128(e) x BN=256(d, full) x BK=64, split-K=4 (1024 m each).
// 512 threads = 8 waves (2x4 of 64x64 tiles). Grid 256, b=f&7 (batch per XCD).
__global__ __launch_bounds__(512, 2) void k_gemm0(const float* __restrict__ inc,
                                                  const float* __restrict__ nf,
                                                  float* __restrict__ P) {
  __shared__ u16 As[2][128][72];
  __shared__ u16 Bs[2][256][72];
  int f = blockIdx.x;
  int b = f & 7, s = f >> 3;
  int eb = s & 7, kc = s >> 3;
  int r0 = eb * 128;
  const float* Ab = inc + (long)b * M_ * E_ + (long)kc * 1024 * E_;  // [m][e]
  const float* Bb = nf + (long)b * M_ * D_ + (long)kc * 1024 * D_;   // [m][d]
  int t = threadIdx.x, l = t & 63, w = t >> 6;
  int l15 = l & 15, lg = l >> 4;
  int we = (w >> 2) * 64, wd = (w & 3) * 64;

  int am = (t >> 5) * 4;        // A m-rows am..am+3
  int ae = (t & 31) * 4;        // A e-cols ae..ae+3
  int bm = (t >> 6) * 8;        // B m-rows bm..bm+7
  int bd = (t & 63) * 4;        // B d-cols bd..bd+3

  fv4 acc[4][4] = {};
  fv4 pa[4], pb[8];

  auto LOAD = [&](int k0) {
#pragma unroll
    for (int r = 0; r < 4; ++r)
      pa[r] = *reinterpret_cast<const fv4*>(Ab + (long)(k0 + am + r) * E_ + r0 + ae);
#pragma unroll
    for (int r = 0; r < 8; ++r)
      pb[r] = *reinterpret_cast<const fv4*>(Bb + (long)(k0 + bm + r) * D_ + bd);
  };
  auto WRITE = [&](int buf) {
    int ga = am >> 3, offa = am & 7;
#pragma unroll
    for (int j = 0; j < 4; ++j) {
      int e = ae + j;
      int colw = ((ga ^ xf(e)) << 3) + offa;
      uint2 va;
      va.x = cvtpk(pa[0][j], pa[1][j]);
      va.y = cvtpk(pa[2][j], pa[3][j]);
      *reinterpret_cast<uint2*>(&As[buf][e][colw]) = va;
    }
    int gb = bm >> 3;
#pragma unroll
    for (int j = 0; j < 4; ++j) {
      int d = bd + j;
      int colw = (gb ^ xf(d)) << 3;
      uint4 vb;
      vb.x = cvtpk(pb[0][j], pb[1][j]);
      vb.y = cvtpk(pb[2][j], pb[3][j]);
      vb.z = cvtpk(pb[4][j], pb[5][j]);
      vb.w = cvtpk(pb[6][j], pb[7][j]);
      *reinterpret_cast<uint4*>(&Bs[buf][d][colw]) = vb;
    }
  };
  auto COMPUTE = [&](int buf) {
#pragma unroll
    for (int kk = 0; kk < 2; ++kk) {
      int gc = kk * 4 + lg;
      bh8 af[4], bf[4];
#pragma unroll
      for (int i = 0; i < 4; ++i) {
        int e = we + i * 16 + l15;
        af[i] = *reinterpret_cast<const bh8*>(&As[buf][e][(gc ^ xf(e)) << 3]);
      }
#pragma unroll
      for (int jj = 0; jj < 4; ++jj) {
        int d = wd + jj * 16 + l15;
        bf[jj] = *reinterpret_cast<const bh8*>(&Bs[buf][d][(gc ^ xf(d)) << 3]);
      }
#pragma unroll
      for (int i = 0; i < 4; ++i)
#pragma unroll
        for (int jj = 0; jj < 4; ++jj)
          acc[i][jj] = __builtin_amdgcn_mfma_f32_16x16x32_bf16(af[i], bf[jj], acc[i][jj], 0, 0, 0);
    }
  };

  LOAD(0);
  WRITE(0);
  __syncthreads();
  const int NIT = 16;  // 1024 / 64
  for (int kt = 0; kt < NIT; ++kt) {
    if (kt < NIT - 1) LOAD((kt + 1) * 64);
    COMPUTE(kt & 1);
    if (kt < NIT - 1) {
      WRITE((kt + 1) & 1);
      __syncthreads();
    }
  }

  float* Pp = P + ((long)(kc * B_ + b) * E_ + r0) * D_;
#pragma unroll
  for (int i = 0; i < 4; ++i)
#pragma unroll
    for (int jj = 0; jj < 4; ++jj)
#pragma unroll
      for (int q = 0; q < 4; ++q) {
        int row = we + i * 16 + lg * 4 + q;
        int col = wd + jj * 16 + l15;
        Pp[(long)row * D_ + col] = acc[i][jj][q];
      }
}

// ---------- reduce 4 split-K partials -> G bf16 ----------
__global__ __launch_bounds__(256) void k_red(const float* __restrict__ P, u16* __restrict__ G) {
  const long CS = (long)B_ * E_ * D_;
  long i = ((long)blockIdx.x * 256 + threadIdx.x) * 4;
  fv4 s0 = *reinterpret_cast<const fv4*>(P + i);
  fv4 s1 = *reinterpret_cast<const fv4*>(P + CS + i);
  fv4 s2 = *reinterpret_cast<const fv4*>(P + 2 * CS + i);
  fv4 s3 = *reinterpret_cast<const fv4*>(P + 3 * CS + i);
  fv4 sum = (s0 + s1) + (s2 + s3);
  uint2 o;
  o.x = cvtpk(sum[0], sum[1]);
  o.y = cvtpk(sum[2], sum[3]);
  *reinterpret_cast<uint2*>(G + i) = o;
}

// ---------- small-K GEMM: out = A' @ W^T (W read f32, converted on the fly) ----------
// MODE 2: A'=G bf16, write S f32 + per-block column softmax partial stats (seg y of 16).
// MODE 1: A'=H=G*exp(S-mx)*sv; mx/sv computed in prologue from mxp/smp (cstats fused);
//         ef = alpha*edge+(1-alpha)*C; fused z-partials -> zp.
template <int MODE>
__global__ __launch_bounds__(256, 2) void k_gemmS(
    const u16* __restrict__ A, const float* __restrict__ Wf,
    const float* __restrict__ Sin,
    float* __restrict__ Sout, float* __restrict__ mxp, float* __restrict__ smp,
    const float* __restrict__ edge, const float* __restrict__ alphap,
    float* __restrict__ outEF, const float* __restrict__ attw, float* __restrict__ zp) {
  __shared__ u16 As[2][64][72];
  __shared__ u16 Bs[2][64][72];
  __shared__ float sM[2][64], sS[2][64];
  __shared__ float sMx[D_], sSv[D_];
  int f = blockIdx.x;
  int b = f & 7, s = f >> 3;
  int x = s & 3, y = s >> 2;
  int r0 = y * 64, c0 = x * 64;
  const u16* Ab = A + (long)b * E_ * D_;
  int t = threadIdx.x, l = t & 63, w = t >> 6;
  int wr = w >> 1, wc = w & 1;
  int l15 = l & 15, lg = l >> 4;
  int rA = t >> 2, kA = (t & 3) * 16;

  if (MODE == 1) {
    // fused cstats2: per-column mx, 1/sum from 16 segments (t = d, 0..255)
    float M = -3.0e38f;
#pragma unroll
    for (int s2 = 0; s2 < 16; ++s2) M = fmaxf(M, mxp[(b * 16 + s2) * D_ + t]);
    float Ssum = 0.f;
#pragma unroll
    for (int s2 = 0; s2 < 16; ++s2)
      Ssum += smp[(b * 16 + s2) * D_ + t] * __expf(mxp[(b * 16 + s2) * D_ + t] - M);
    sMx[t] = M;
    sSv[t] = 1.0f / Ssum;
  }
  __syncthreads();  // sMx/sSv visible to ALL threads before any WRITE uses them

  fv4 acc[2][2] = {};
  bh8 ga0[2], ga1[2];
  fv4 gb0[4], gb1[4];
  fv4 sa0[4], sa1[4];

  auto LOAD = [&](int k0, bh8 (&ga)[2], fv4 (&gb)[4], fv4 (&sa)[4]) {
    const u16* ap = Ab + (long)(r0 + rA) * D_ + k0 + kA;
    const float* bp = Wf + (long)(c0 + rA) * D_ + k0 + kA;
    ga[0] = *reinterpret_cast<const bh8*>(ap);
    ga[1] = *reinterpret_cast<const bh8*>(ap + 8);
#pragma unroll
    for (int i = 0; i < 4; ++i) gb[i] = *reinterpret_cast<const fv4*>(bp + i * 4);
    if (MODE == 1) {
      const float* sp2 = Sin + ((long)b * E_ + r0 + rA) * D_ + k0 + kA;
#pragma unroll
      for (int i = 0; i < 4; ++i) sa[i] = *reinterpret_cast<const fv4*>(sp2 + i * 4);
    }
  };
  auto WRITE = [&](const bh8 (&ga)[2], const fv4 (&gb)[4], const fv4 (&sa)[4], int buf, int k0) {
    if (MODE == 2) {
      *reinterpret_cast<bh8*>(&As[buf][rA][kA]) = ga[0];
      *reinterpret_cast<bh8*>(&As[buf][rA][kA + 8]) = ga[1];
    } else {
#pragma unroll
      for (int h = 0; h < 2; ++h) {
        fv4 mA = *reinterpret_cast<const fv4*>(&sMx[k0 + kA + h * 8]);
        fv4 mB = *reinterpret_cast<const fv4*>(&sMx[k0 + kA + h * 8 + 4]);
        fv4 vA = *reinterpret_cast<const fv4*>(&sSv[k0 + kA + h * 8]);
        fv4 vB = *reinterpret_cast<const fv4*>(&sSv[k0 + kA + h * 8 + 4]);
        float hf[8];
#pragma unroll
        for (int j = 0; j < 4; ++j) {
          hf[j]     = b2f((u16)ga[h][j])     * __expf(sa[h * 2][j]     - mA[j]) * vA[j];
          hf[4 + j] = b2f((u16)ga[h][j + 4]) * __expf(sa[h * 2 + 1][j] - mB[j]) * vB[j];
        }
        union { u32 w4[4]; bh8 v; } hp;
        hp.w4[0] = cvtpk(hf[0], hf[1]);
        hp.w4[1] = cvtpk(hf[2], hf[3]);
        hp.w4[2] = cvtpk(hf[4], hf[5]);
        hp.w4[3] = cvtpk(hf[6], hf[7]);
        *reinterpret_cast<bh8*>(&As[buf][rA][kA + h * 8]) = hp.v;
      }
    }
    union { u32 w4[4]; bh8 v; } wb0, wb1;
    wb0.w4[0] = cvtpk(gb[0][0], gb[0][1]);
    wb0.w4[1] = cvtpk(gb[0][2], gb[0][3]);
    wb0.w4[2] = cvtpk(gb[1][0], gb[1][1]);
    wb0.w4[3] = cvtpk(gb[1][2], gb[1][3]);
    wb1.w4[0] = cvtpk(gb[2][0], gb[2][1]);
    wb1.w4[1] = cvtpk(gb[2][2], gb[2][3]);
    wb1.w4[2] = cvtpk(gb[3][0], gb[3][1]);
    wb1.w4[3] = cvtpk(gb[3][2], gb[3][3]);
    *reinterpret_cast<bh8*>(&Bs[buf][rA][kA]) = wb0.v;
    *reinterpret_cast<bh8*>(&Bs[buf][rA][kA + 8]) = wb1.v;
  };
  auto COMPUTE = [&](int buf) {
#pragma unroll
    for (int kk = 0; kk < 2; ++kk) {
      bh8 af[2], bf[2];
#pragma unroll
      for (int i = 0; i < 2; ++i)
        af[i] = *reinterpret_cast<const bh8*>(&As[buf][wr * 32 + i * 16 + l15][kk * 32 + lg * 8]);
#pragma unroll
      for (int j = 0; j < 2; ++j)
        bf[j] = *reinterpret_cast<const bh8*>(&Bs[buf][wc * 32 + j * 16 + l15][kk * 32 + lg * 8]);
#pragma unroll
      for (int i = 0; i < 2; ++i)
#pragma unroll
        for (int j = 0; j < 2; ++j)
          acc[i][j] = __builtin_amdgcn_mfma_f32_16x16x32_bf16(af[i], bf[j], acc[i][j], 0, 0, 0);
    }
  };

  const int NT = D_ / 64;
  LOAD(0, ga0, gb0, sa0);
  LOAD(64, ga1, gb1, sa1);
  WRITE(ga0, gb0, sa0, 0, 0);
  __syncthreads();
  for (int kt = 0; kt < NT; kt += 2) {
    if (kt + 2 < NT) LOAD((kt + 2) * 64, ga0, gb0, sa0);
    COMPUTE(0);
    WRITE(ga1, gb1, sa1, 1, (kt + 1) * 64);
    __syncthreads();
    if (kt + 3 < NT) LOAD((kt + 3) * 64, ga1, gb1, sa1);
    COMPUTE(1);
    if (kt + 2 < NT) WRITE(ga0, gb0, sa0, 0, (kt + 2) * 64);
    __syncthreads();
  }

  if (MODE == 2) {
#pragma unroll
    for (int i = 0; i < 2; ++i)
#pragma unroll
      for (int j = 0; j < 2; ++j)
#pragma unroll
        for (int q = 0; q < 4; ++q) {
          int row = r0 + wr * 32 + i * 16 + lg * 4 + q;
          int col = c0 + wc * 32 + j * 16 + l15;
          Sout[((long)b * E_ + row) * D_ + col] = acc[i][j][q];
        }
#pragma unroll
    for (int j = 0; j < 2; ++j) {
      float m = -3.0e38f;
#pragma unroll
      for (int i = 0; i < 2; ++i)
#pragma unroll
        for (int q = 0; q < 4; ++q) m = fmaxf(m, acc[i][j][q]);
      m = fmaxf(m, __shfl_xor(m, 16));
      m = fmaxf(m, __shfl_xor(m, 32));
      float ssum = 0.f;
#pragma unroll
      for (int i = 0; i < 2; ++i)
#pragma unroll
        for (int q = 0; q < 4; ++q) ssum += __expf(acc[i][j][q] - m);
      ssum += __shfl_xor(ssum, 16);
      ssum += __shfl_xor(ssum, 32);
      if (lg == 0) {
        sM[wr][wc * 32 + j * 16 + l15] = m;
        sS[wr][wc * 32 + j * 16 + l15] = ssum;
      }
    }
    __syncthreads();
    if (t < 64) {
      float m0 = sM[0][t], m1 = sM[1][t];
      float M = fmaxf(m0, m1);
      float ss = sS[0][t] * __expf(m0 - M) + sS[1][t] * __expf(m1 - M);
      int idx = (b * 16 + y) * D_ + c0 + t;
      mxp[idx] = M;
      smp[idx] = ss;
    }
  } else {
    float al = *alphap, oneal = 1.0f - al;
    float aw0 = attw[c0 + wc * 32 + l15];
    float aw1 = attw[c0 + wc * 32 + 16 + l15];
#pragma unroll
    for (int i = 0; i < 2; ++i)
#pragma unroll
      for (int q = 0; q < 4; ++q) {
        int row = r0 + wr * 32 + i * 16 + lg * 4 + q;
        long idx0 = ((long)b * E_ + row) * D_ + c0 + wc * 32 + l15;
        long idx1 = idx0 + 16;
        float ef0 = al * edge[idx0] + oneal * acc[i][0][q];
        float ef1 = al * edge[idx1] + oneal * acc[i][1][q];
        outEF[idx0] = ef0;
        outEF[idx1] = ef1;
        float zv = ef0 * aw0 + ef1 * aw1;
        zv += __shfl_xor(zv, 1);
        zv += __shfl_xor(zv, 2);
        zv += __shfl_xor(zv, 4);
        zv += __shfl_xor(zv, 8);
        if (l15 == 0) zp[((long)(x * 2 + wc) * B_ + b) * E_ + row] = zv;
      }
  }
}

// ---------- fused tail: softmax over e of z -> pooled -> proj -> fc ----------
// grid B_, 1024 threads (16 waves).
__global__ __launch_bounds__(1024) void k_tail(const float* __restrict__ zp, const float* __restrict__ ef,
                                               const float* __restrict__ projw, const float* __restrict__ projb,
                                               const float* __restrict__ fcw, const float* __restrict__ fcb,
                                               float* __restrict__ outp) {
  int b = blockIdx.x, t = threadIdx.x;
  __shared__ float wred[16];
  __shared__ float sAz[E_];
  __shared__ float ps[4][D_];
  __shared__ float spl[D_], ov[D_];
  // z = sum of 8 zp slices; block softmax over e=0..1023
  float v = 0.f;
#pragma unroll
  for (int s = 0; s < 8; ++s) v += zp[((long)s * B_ + b) * E_ + t];
  float m = v;
#pragma unroll
  for (int off = 32; off; off >>= 1) m = fmaxf(m, __shfl_xor(m, off));
  if ((t & 63) == 0) wred[t >> 6] = m;
  __syncthreads();
  m = wred[0];
#pragma unroll
  for (int i = 1; i < 16; ++i) m = fmaxf(m, wred[i]);
  float ez = __expf(v - m);
  float ssum = ez;
#pragma unroll
  for (int off = 32; off; off >>= 1) ssum += __shfl_xor(ssum, off);
  __syncthreads();
  if ((t & 63) == 0) wred[t >> 6] = ssum;
  __syncthreads();
  ssum = 0.f;
#pragma unroll
  for (int i = 0; i < 16; ++i) ssum += wred[i];
  float inv = 1.0f / ssum;
  sAz[t] = ez * inv;
  __syncthreads();
  // pooled[d] = sum_e az[e] * ef[b][e][d]
  int d = t & 255, g = t >> 8;
  float a = 0.f;
  for (int e = g; e < E_; e += 4)
    a += sAz[e] * ef[((long)b * E_ + e) * D_ + d];
  ps[g][d] = a;
  __syncthreads();
  if (t < D_) spl[t] = ps[0][t] + ps[1][t] + ps[2][t] + ps[3][t];
  __syncthreads();
  if (t < D_) {
    float o = projb[t];
    for (int dd = 0; dd < D_; ++dd) o += projw[t * D_ + dd] * spl[dd];
    ov[t] = o;
  }
  __syncthreads();
  if (t < C_) {
    float lg = fcb[t];
    for (int dd = 0; dd < D_; ++dd) lg += fcw[t * D_ + dd] * ov[dd];
    outp[b * C_ + t] = lg;
  }
}

extern "C" void kernel_launch(void* const* d_in, const int* in_sizes, int n_in,
                              void* d_out, int out_size, void* d_ws, size_t ws_size,
                              hipStream_t stream) {
  const float* node  = (const float*)d_in[0];
  const float* edge  = (const float*)d_in[1];
  const float* inc   = (const float*)d_in[2];
  const float* Wa    = (const float*)d_in[3];
  const float* Wp    = (const float*)d_in[4];
  const float* alpha = (const float*)d_in[5];
  const float* attw  = (const float*)d_in[6];
  const float* projw = (const float*)d_in[7];
  const float* projb = (const float*)d_in[8];
  const float* fcw   = (const float*)d_in[9];
  const float* fcb   = (const float*)d_in[10];
  float* outp = (float*)d_out;

  char* wsp = (char*)d_ws;
  size_t off = 0;
  auto alloc = [&](size_t bytes) {
    char* p = wsp + off;
    off += (bytes + 255) & ~(size_t)255;
    return (void*)p;
  };
  // P (4 x 8.4MB) dead after k_red; S and ef alias the region.
  float* P  = (float*)alloc((size_t)4 * B_ * E_ * D_ * 4);
  float* S  = P;                                  // written after k_red (P dead)
  float* ef = P + (size_t)2 * B_ * E_ * D_;       // written while S (lower half) is read
  u16* G    = (u16*)alloc((size_t)B_ * E_ * D_ * 2);
  float* mxp = (float*)alloc((size_t)B_ * 16 * D_ * 4);
  float* smp = (float*)alloc((size_t)B_ * 16 * D_ * 4);
  float* zp  = (float*)alloc((size_t)8 * B_ * E_ * 4);

  // 1. split-K partials P[kc] = inc^T @ nf (r11 structure)
  k_gemm0<<<dim3(256), 512, 0, stream>>>(inc, node, P);
  // 2. reduce partials -> G bf16
  k_red<<<dim3((B_ * E_ * D_) / 1024), 256, 0, stream>>>(P, G);
  // 3. S = G @ Wa^T (f32, Wa converted on the fly) + partial column softmax stats
  k_gemmS<2><<<dim3(512), 256, 0, stream>>>(G, Wa, nullptr,
                                            S, mxp, smp, nullptr, nullptr, nullptr, nullptr, nullptr);
  // 4. ef = alpha*edge + (1-alpha)*((G*softmax) @ Wp^T); cstats + z-partials fused
  k_gemmS<1><<<dim3(512), 256, 0, stream>>>(G, Wp, S,
                                            nullptr, mxp, smp, edge, alpha, ef, attw, zp);
  // 5. fused tail: z-softmax -> pooled -> proj -> logits
  k_tail<<<dim3(B_), 1024, 0, stream>>>(zp, ef, projw, projb, fcw, fcb, outp);
}

// Round 15
// 90.901 us; speedup vs baseline: 1.8292x; 1.7026x over previous
//
#include <hip/hip_runtime.h>

#define B_ 8
#define M_ 4096
#define E_ 1024
#define D_ 256
#define C_ 16

typedef unsigned short u16;
typedef unsigned int u32;
typedef float fv4 __attribute__((ext_vector_type(4)));
typedef short bh8 __attribute__((ext_vector_type(8)));

__device__ __forceinline__ float b2f(u16 v) { return __uint_as_float(((unsigned)v) << 16); }
__device__ __forceinline__ u16 f2b(float f) {
  unsigned u = __float_as_uint(f);
  return (u16)((u + 0x7FFFu + ((u >> 16) & 1u)) >> 16);
}
// packs lo -> low 16 bits, hi -> high 16 bits, RNE
__device__ __forceinline__ u32 cvtpk(float lo, float hi) {
  u32 r;
  asm("v_cvt_pk_bf16_f32 %0, %1, %2" : "=v"(r) : "v"(lo), "v"(hi));
  return r;
}
// per-row granule swizzle (16B granules, 8 per 64-u16 row segment)
__device__ __forceinline__ int xf(int r) { return ((r >> 2) ^ (r >> 5)) & 7; }

// ---------- split-K partial GEMM: P[kc] = inc^T @ nf over m-chunk (r11 verbatim) ----------
// BM=128(e) x BN=256(d, full) x BK=64, split-K=4 (1024 m each).
// 512 threads = 8 waves (2x4 of 64x64 tiles). Grid 256, b=f&7 (batch per XCD).
__global__ __launch_bounds__(512, 2) void k_gemm0(const float* __restrict__ inc,
                                                  const float* __restrict__ nf,
                                                  float* __restrict__ P) {
  __shared__ u16 As[2][128][72];
  __shared__ u16 Bs[2][256][72];
  int f = blockIdx.x;
  int b = f & 7, s = f >> 3;
  int eb = s & 7, kc = s >> 3;
  int r0 = eb * 128;
  const float* Ab = inc + (long)b * M_ * E_ + (long)kc * 1024 * E_;  // [m][e]
  const float* Bb = nf + (long)b * M_ * D_ + (long)kc * 1024 * D_;   // [m][d]
  int t = threadIdx.x, l = t & 63, w = t >> 6;
  int l15 = l & 15, lg = l >> 4;
  int we = (w >> 2) * 64, wd = (w & 3) * 64;

  int am = (t >> 5) * 4;        // A m-rows am..am+3
  int ae = (t & 31) * 4;        // A e-cols ae..ae+3
  int bm = (t >> 6) * 8;        // B m-rows bm..bm+7
  int bd = (t & 63) * 4;        // B d-cols bd..bd+3

  fv4 acc[4][4] = {};
  fv4 pa[4], pb[8];

  auto LOAD = [&](int k0) {
#pragma unroll
    for (int r = 0; r < 4; ++r)
      pa[r] = *reinterpret_cast<const fv4*>(Ab + (long)(k0 + am + r) * E_ + r0 + ae);
#pragma unroll
    for (int r = 0; r < 8; ++r)
      pb[r] = *reinterpret_cast<const fv4*>(Bb + (long)(k0 + bm + r) * D_ + bd);
  };
  auto WRITE = [&](int buf) {
    int ga = am >> 3, offa = am & 7;
#pragma unroll
    for (int j = 0; j < 4; ++j) {
      int e = ae + j;
      int colw = ((ga ^ xf(e)) << 3) + offa;
      uint2 va;
      va.x = cvtpk(pa[0][j], pa[1][j]);
      va.y = cvtpk(pa[2][j], pa[3][j]);
      *reinterpret_cast<uint2*>(&As[buf][e][colw]) = va;
    }
    int gb = bm >> 3;
#pragma unroll
    for (int j = 0; j < 4; ++j) {
      int d = bd + j;
      int colw = (gb ^ xf(d)) << 3;
      uint4 vb;
      vb.x = cvtpk(pb[0][j], pb[1][j]);
      vb.y = cvtpk(pb[2][j], pb[3][j]);
      vb.z = cvtpk(pb[4][j], pb[5][j]);
      vb.w = cvtpk(pb[6][j], pb[7][j]);
      *reinterpret_cast<uint4*>(&Bs[buf][d][colw]) = vb;
    }
  };
  auto COMPUTE = [&](int buf) {
#pragma unroll
    for (int kk = 0; kk < 2; ++kk) {
      int gc = kk * 4 + lg;
      bh8 af[4], bf[4];
#pragma unroll
      for (int i = 0; i < 4; ++i) {
        int e = we + i * 16 + l15;
        af[i] = *reinterpret_cast<const bh8*>(&As[buf][e][(gc ^ xf(e)) << 3]);
      }
#pragma unroll
      for (int jj = 0; jj < 4; ++jj) {
        int d = wd + jj * 16 + l15;
        bf[jj] = *reinterpret_cast<const bh8*>(&Bs[buf][d][(gc ^ xf(d)) << 3]);
      }
#pragma unroll
      for (int i = 0; i < 4; ++i)
#pragma unroll
        for (int jj = 0; jj < 4; ++jj)
          acc[i][jj] = __builtin_amdgcn_mfma_f32_16x16x32_bf16(af[i], bf[jj], acc[i][jj], 0, 0, 0);
    }
  };

  LOAD(0);
  WRITE(0);
  __syncthreads();
  const int NIT = 16;  // 1024 / 64
  for (int kt = 0; kt < NIT; ++kt) {
    if (kt < NIT - 1) LOAD((kt + 1) * 64);
    COMPUTE(kt & 1);
    if (kt < NIT - 1) {
      WRITE((kt + 1) & 1);
      __syncthreads();
    }
  }

  float* Pp = P + ((long)(kc * B_ + b) * E_ + r0) * D_;
#pragma unroll
  for (int i = 0; i < 4; ++i)
#pragma unroll
    for (int jj = 0; jj < 4; ++jj)
#pragma unroll
      for (int q = 0; q < 4; ++q) {
        int row = we + i * 16 + lg * 4 + q;
        int col = wd + jj * 16 + l15;
        Pp[(long)row * D_ + col] = acc[i][jj][q];
      }
}

// ---------- reduce 4 split-K partials -> G bf16 ----------
__global__ __launch_bounds__(256) void k_red(const float* __restrict__ P, u16* __restrict__ G) {
  const long CS = (long)B_ * E_ * D_;
  long i = ((long)blockIdx.x * 256 + threadIdx.x) * 4;
  fv4 s0 = *reinterpret_cast<const fv4*>(P + i);
  fv4 s1 = *reinterpret_cast<const fv4*>(P + CS + i);
  fv4 s2 = *reinterpret_cast<const fv4*>(P + 2 * CS + i);
  fv4 s3 = *reinterpret_cast<const fv4*>(P + 3 * CS + i);
  fv4 sum = (s0 + s1) + (s2 + s3);
  uint2 o;
  o.x = cvtpk(sum[0], sum[1]);
  o.y = cvtpk(sum[2], sum[3]);
  *reinterpret_cast<uint2*>(G + i) = o;
}

// ---------- small-K GEMM: out = A' @ W^T (W read f32, converted on the fly) ----------
// MODE 2: A'=G bf16, write S f32 + per-block column softmax partial stats (seg y of 16).
// MODE 1: A'=H=G*exp(S-mx)*sv; mx/sv computed in prologue from mxp/smp (cstats fused);
//         ef = alpha*edge+(1-alpha)*C; fused z-partials -> zp.
template <int MODE>
__global__ __launch_bounds__(256, 2) void k_gemmS(
    const u16* __restrict__ A, const float* __restrict__ Wf,
    const float* __restrict__ Sin,
    float* __restrict__ Sout, float* __restrict__ mxp, float* __restrict__ smp,
    const float* __restrict__ edge, const float* __restrict__ alphap,
    float* __restrict__ outEF, const float* __restrict__ attw, float* __restrict__ zp) {
  __shared__ u16 As[2][64][72];
  __shared__ u16 Bs[2][64][72];
  __shared__ float sM[2][64], sS[2][64];
  __shared__ float sMx[D_], sSv[D_];
  int f = blockIdx.x;
  int b = f & 7, s = f >> 3;
  int x = s & 3, y = s >> 2;
  int r0 = y * 64, c0 = x * 64;
  const u16* Ab = A + (long)b * E_ * D_;
  int t = threadIdx.x, l = t & 63, w = t >> 6;
  int wr = w >> 1, wc = w & 1;
  int l15 = l & 15, lg = l >> 4;
  int rA = t >> 2, kA = (t & 3) * 16;

  if (MODE == 1) {
    // fused cstats2: per-column mx, 1/sum from 16 segments (t = d, 0..255)
    float M = -3.0e38f;
#pragma unroll
    for (int s2 = 0; s2 < 16; ++s2) M = fmaxf(M, mxp[(b * 16 + s2) * D_ + t]);
    float Ssum = 0.f;
#pragma unroll
    for (int s2 = 0; s2 < 16; ++s2)
      Ssum += smp[(b * 16 + s2) * D_ + t] * __expf(mxp[(b * 16 + s2) * D_ + t] - M);
    sMx[t] = M;
    sSv[t] = 1.0f / Ssum;
  }
  __syncthreads();  // sMx/sSv visible to ALL threads before any WRITE uses them

  fv4 acc[2][2] = {};
  bh8 ga0[2], ga1[2];
  fv4 gb0[4], gb1[4];
  fv4 sa0[4], sa1[4];

  auto LOAD = [&](int k0, bh8 (&ga)[2], fv4 (&gb)[4], fv4 (&sa)[4]) {
    const u16* ap = Ab + (long)(r0 + rA) * D_ + k0 + kA;
    const float* bp = Wf + (long)(c0 + rA) * D_ + k0 + kA;
    ga[0] = *reinterpret_cast<const bh8*>(ap);
    ga[1] = *reinterpret_cast<const bh8*>(ap + 8);
#pragma unroll
    for (int i = 0; i < 4; ++i) gb[i] = *reinterpret_cast<const fv4*>(bp + i * 4);
    if (MODE == 1) {
      const float* sp2 = Sin + ((long)b * E_ + r0 + rA) * D_ + k0 + kA;
#pragma unroll
      for (int i = 0; i < 4; ++i) sa[i] = *reinterpret_cast<const fv4*>(sp2 + i * 4);
    }
  };
  auto WRITE = [&](const bh8 (&ga)[2], const fv4 (&gb)[4], const fv4 (&sa)[4], int buf, int k0) {
    if (MODE == 2) {
      *reinterpret_cast<bh8*>(&As[buf][rA][kA]) = ga[0];
      *reinterpret_cast<bh8*>(&As[buf][rA][kA + 8]) = ga[1];
    } else {
#pragma unroll
      for (int h = 0; h < 2; ++h) {
        fv4 mA = *reinterpret_cast<const fv4*>(&sMx[k0 + kA + h * 8]);
        fv4 mB = *reinterpret_cast<const fv4*>(&sMx[k0 + kA + h * 8 + 4]);
        fv4 vA = *reinterpret_cast<const fv4*>(&sSv[k0 + kA + h * 8]);
        fv4 vB = *reinterpret_cast<const fv4*>(&sSv[k0 + kA + h * 8 + 4]);
        float hf[8];
#pragma unroll
        for (int j = 0; j < 4; ++j) {
          hf[j]     = b2f((u16)ga[h][j])     * __expf(sa[h * 2][j]     - mA[j]) * vA[j];
          hf[4 + j] = b2f((u16)ga[h][j + 4]) * __expf(sa[h * 2 + 1][j] - mB[j]) * vB[j];
        }
        union { u32 w4[4]; bh8 v; } hp;
        hp.w4[0] = cvtpk(hf[0], hf[1]);
        hp.w4[1] = cvtpk(hf[2], hf[3]);
        hp.w4[2] = cvtpk(hf[4], hf[5]);
        hp.w4[3] = cvtpk(hf[6], hf[7]);
        *reinterpret_cast<bh8*>(&As[buf][rA][kA + h * 8]) = hp.v;
      }
    }
    union { u32 w4[4]; bh8 v; } wb0, wb1;
    wb0.w4[0] = cvtpk(gb[0][0], gb[0][1]);
    wb0.w4[1] = cvtpk(gb[0][2], gb[0][3]);
    wb0.w4[2] = cvtpk(gb[1][0], gb[1][1]);
    wb0.w4[3] = cvtpk(gb[1][2], gb[1][3]);
    wb1.w4[0] = cvtpk(gb[2][0], gb[2][1]);
    wb1.w4[1] = cvtpk(gb[2][2], gb[2][3]);
    wb1.w4[2] = cvtpk(gb[3][0], gb[3][1]);
    wb1.w4[3] = cvtpk(gb[3][2], gb[3][3]);
    *reinterpret_cast<bh8*>(&Bs[buf][rA][kA]) = wb0.v;
    *reinterpret_cast<bh8*>(&Bs[buf][rA][kA + 8]) = wb1.v;
  };
  auto COMPUTE = [&](int buf) {
#pragma unroll
    for (int kk = 0; kk < 2; ++kk) {
      bh8 af[2], bf[2];
#pragma unroll
      for (int i = 0; i < 2; ++i)
        af[i] = *reinterpret_cast<const bh8*>(&As[buf][wr * 32 + i * 16 + l15][kk * 32 + lg * 8]);
#pragma unroll
      for (int j = 0; j < 2; ++j)
        bf[j] = *reinterpret_cast<const bh8*>(&Bs[buf][wc * 32 + j * 16 + l15][kk * 32 + lg * 8]);
#pragma unroll
      for (int i = 0; i < 2; ++i)
#pragma unroll
        for (int j = 0; j < 2; ++j)
          acc[i][j] = __builtin_amdgcn_mfma_f32_16x16x32_bf16(af[i], bf[j], acc[i][j], 0, 0, 0);
    }
  };

  const int NT = D_ / 64;
  LOAD(0, ga0, gb0, sa0);
  LOAD(64, ga1, gb1, sa1);
  WRITE(ga0, gb0, sa0, 0, 0);
  __syncthreads();
  for (int kt = 0; kt < NT; kt += 2) {
    if (kt + 2 < NT) LOAD((kt + 2) * 64, ga0, gb0, sa0);
    COMPUTE(0);
    WRITE(ga1, gb1, sa1, 1, (kt + 1) * 64);
    __syncthreads();
    if (kt + 3 < NT) LOAD((kt + 3) * 64, ga1, gb1, sa1);
    COMPUTE(1);
    if (kt + 2 < NT) WRITE(ga0, gb0, sa0, 0, (kt + 2) * 64);
    __syncthreads();
  }

  if (MODE == 2) {
#pragma unroll
    for (int i = 0; i < 2; ++i)
#pragma unroll
      for (int j = 0; j < 2; ++j)
#pragma unroll
        for (int q = 0; q < 4; ++q) {
          int row = r0 + wr * 32 + i * 16 + lg * 4 + q;
          int col = c0 + wc * 32 + j * 16 + l15;
          Sout[((long)b * E_ + row) * D_ + col] = acc[i][j][q];
        }
#pragma unroll
    for (int j = 0; j < 2; ++j) {
      float m = -3.0e38f;
#pragma unroll
      for (int i = 0; i < 2; ++i)
#pragma unroll
        for (int q = 0; q < 4; ++q) m = fmaxf(m, acc[i][j][q]);
      m = fmaxf(m, __shfl_xor(m, 16));
      m = fmaxf(m, __shfl_xor(m, 32));
      float ssum = 0.f;
#pragma unroll
      for (int i = 0; i < 2; ++i)
#pragma unroll
        for (int q = 0; q < 4; ++q) ssum += __expf(acc[i][j][q] - m);
      ssum += __shfl_xor(ssum, 16);
      ssum += __shfl_xor(ssum, 32);
      if (lg == 0) {
        sM[wr][wc * 32 + j * 16 + l15] = m;
        sS[wr][wc * 32 + j * 16 + l15] = ssum;
      }
    }
    __syncthreads();
    if (t < 64) {
      float m0 = sM[0][t], m1 = sM[1][t];
      float M = fmaxf(m0, m1);
      float ss = sS[0][t] * __expf(m0 - M) + sS[1][t] * __expf(m1 - M);
      int idx = (b * 16 + y) * D_ + c0 + t;
      mxp[idx] = M;
      smp[idx] = ss;
    }
  } else {
    float al = *alphap, oneal = 1.0f - al;
    float aw0 = attw[c0 + wc * 32 + l15];
    float aw1 = attw[c0 + wc * 32 + 16 + l15];
#pragma unroll
    for (int i = 0; i < 2; ++i)
#pragma unroll
      for (int q = 0; q < 4; ++q) {
        int row = r0 + wr * 32 + i * 16 + lg * 4 + q;
        long idx0 = ((long)b * E_ + row) * D_ + c0 + wc * 32 + l15;
        long idx1 = idx0 + 16;
        float ef0 = al * edge[idx0] + oneal * acc[i][0][q];
        float ef1 = al * edge[idx1] + oneal * acc[i][1][q];
        outEF[idx0] = ef0;
        outEF[idx1] = ef1;
        float zv = ef0 * aw0 + ef1 * aw1;
        zv += __shfl_xor(zv, 1);
        zv += __shfl_xor(zv, 2);
        zv += __shfl_xor(zv, 4);
        zv += __shfl_xor(zv, 8);
        if (l15 == 0) zp[((long)(x * 2 + wc) * B_ + b) * E_ + row] = zv;
      }
  }
}

// ---------- tail A: redundant z-softmax + partial pooled over 128 e-rows ----------
// grid (8 segs, B), 256 thr. pp[b][seg][d] = sum_{e in seg} az[e]*ef[b][e][d].
__global__ __launch_bounds__(256) void k_tailA(const float* __restrict__ zp, const float* __restrict__ ef,
                                               float* __restrict__ pp) {
  int seg = blockIdx.x, b = blockIdx.y;
  int t = threadIdx.x;
  __shared__ float sZ[E_];
  __shared__ float wred[4];
  __shared__ float ps[4][D_];
  // z = sum of 8 zp slices (each thread owns 4 e)
  fv4 v = {};
#pragma unroll
  for (int s = 0; s < 8; ++s)
    v += *reinterpret_cast<const fv4*>(zp + ((long)s * B_ + b) * E_ + t * 4);
  *reinterpret_cast<fv4*>(&sZ[t * 4]) = v;
  // block max
  float m = fmaxf(fmaxf(v[0], v[1]), fmaxf(v[2], v[3]));
#pragma unroll
  for (int off = 32; off; off >>= 1) m = fmaxf(m, __shfl_xor(m, off));
  if ((t & 63) == 0) wred[t >> 6] = m;
  __syncthreads();
  m = fmaxf(fmaxf(wred[0], wred[1]), fmaxf(wred[2], wred[3]));
  float e0 = __expf(v[0] - m), e1 = __expf(v[1] - m), e2 = __expf(v[2] - m), e3 = __expf(v[3] - m);
  float ssum = e0 + e1 + e2 + e3;
#pragma unroll
  for (int off = 32; off; off >>= 1) ssum += __shfl_xor(ssum, off);
  __syncthreads();
  if ((t & 63) == 0) wred[t >> 6] = ssum;
  __syncthreads();
  ssum = wred[0] + wred[1] + wred[2] + wred[3];
  float inv = 1.0f / ssum;
  fv4 az;
  az[0] = e0 * inv; az[1] = e1 * inv; az[2] = e2 * inv; az[3] = e3 * inv;
  __syncthreads();  // sZ fully written (it already is), reuse as az store
  *reinterpret_cast<fv4*>(&sZ[t * 4]) = az;
  __syncthreads();
  // partial pooled over this segment's 128 e-rows; group g handles 32 rows
  int g = t >> 6, l = t & 63;
  fv4 a = {};
  const float* efb = ef + ((long)b * E_ + seg * 128 + g * 32) * D_ + l * 4;
  const float* azp = &sZ[seg * 128 + g * 32];
#pragma unroll 4
  for (int i = 0; i < 32; ++i)
    a += azp[i] * *reinterpret_cast<const fv4*>(efb + (long)i * D_);
  *reinterpret_cast<fv4*>(&ps[g][l * 4]) = a;
  __syncthreads();
  if (t < D_)
    pp[((long)b * 8 + seg) * D_ + t] = ps[0][t] + ps[1][t] + ps[2][t] + ps[3][t];
}

// ---------- tail B: pooled = sum segs; proj; fc -> logits ----------
__global__ __launch_bounds__(256) void k_tailB(const float* __restrict__ pp,
                                               const float* __restrict__ projw, const float* __restrict__ projb,
                                               const float* __restrict__ fcw, const float* __restrict__ fcb,
                                               float* __restrict__ outp) {
  int b = blockIdx.x, t = threadIdx.x;
  __shared__ float spl[D_], ov[D_];
  float a = 0.f;
#pragma unroll
  for (int s = 0; s < 8; ++s) a += pp[((long)b * 8 + s) * D_ + t];
  spl[t] = a;
  __syncthreads();
  float o = projb[t];
  const fv4* pw = reinterpret_cast<const fv4*>(projw + (long)t * D_);
#pragma unroll 8
  for (int dd = 0; dd < D_ / 4; ++dd) {
    fv4 wv = pw[dd];
    fv4 pv = *reinterpret_cast<const fv4*>(&spl[dd * 4]);
    o += wv[0] * pv[0] + wv[1] * pv[1] + wv[2] * pv[2] + wv[3] * pv[3];
  }
  ov[t] = o;
  __syncthreads();
  if (t < C_) {
    float lg = fcb[t];
    const fv4* fw = reinterpret_cast<const fv4*>(fcw + (long)t * D_);
#pragma unroll 8
    for (int dd = 0; dd < D_ / 4; ++dd) {
      fv4 wv = fw[dd];
      fv4 pv = *reinterpret_cast<const fv4*>(&ov[dd * 4]);
      lg += wv[0] * pv[0] + wv[1] * pv[1] + wv[2] * pv[2] + wv[3] * pv[3];
    }
    outp[b * C_ + t] = lg;
  }
}

extern "C" void kernel_launch(void* const* d_in, const int* in_sizes, int n_in,
                              void* d_out, int out_size, void* d_ws, size_t ws_size,
                              hipStream_t stream) {
  const float* node  = (const float*)d_in[0];
  const float* edge  = (const float*)d_in[1];
  const float* inc   = (const float*)d_in[2];
  const float* Wa    = (const float*)d_in[3];
  const float* Wp    = (const float*)d_in[4];
  const float* alpha = (const float*)d_in[5];
  const float* attw  = (const float*)d_in[6];
  const float* projw = (const float*)d_in[7];
  const float* projb = (const float*)d_in[8];
  const float* fcw   = (const float*)d_in[9];
  const float* fcb   = (const float*)d_in[10];
  float* outp = (float*)d_out;

  char* wsp = (char*)d_ws;
  size_t off = 0;
  auto alloc = [&](size_t bytes) {
    char* p = wsp + off;
    off += (bytes + 255) & ~(size_t)255;
    return (void*)p;
  };
  // P (4 x 8.4MB) dead after k_red; S and ef alias the region.
  float* P  = (float*)alloc((size_t)4 * B_ * E_ * D_ * 4);
  float* S  = P;                                  // written after k_red (P dead)
  float* ef = P + (size_t)2 * B_ * E_ * D_;       // written while S (lower half) is read
  u16* G    = (u16*)alloc((size_t)B_ * E_ * D_ * 2);
  float* mxp = (float*)alloc((size_t)B_ * 16 * D_ * 4);
  float* smp = (float*)alloc((size_t)B_ * 16 * D_ * 4);
  float* zp  = (float*)alloc((size_t)8 * B_ * E_ * 4);
  float* pp  = (float*)alloc((size_t)B_ * 8 * D_ * 4);

  // 1. split-K partials P[kc] = inc^T @ nf (r11 structure)
  k_gemm0<<<dim3(256), 512, 0, stream>>>(inc, node, P);
  // 2. reduce partials -> G bf16
  k_red<<<dim3((B_ * E_ * D_) / 1024), 256, 0, stream>>>(P, G);
  // 3. S = G @ Wa^T (f32, Wa converted on the fly) + partial column softmax stats
  k_gemmS<2><<<dim3(512), 256, 0, stream>>>(G, Wa, nullptr,
                                            S, mxp, smp, nullptr, nullptr, nullptr, nullptr, nullptr);
  // 4. ef = alpha*edge + (1-alpha)*((G*softmax) @ Wp^T); cstats + z-partials fused
  k_gemmS<1><<<dim3(512), 256, 0, stream>>>(G, Wp, S,
                                            nullptr, mxp, smp, edge, alpha, ef, attw, zp);
  // 5. tail A: redundant z-softmax + partial pooled (64 blocks)
  k_tailA<<<dim3(8, B_), 256, 0, stream>>>(zp, ef, pp);
  // 6. tail B: combine + proj + logits
  k_tailB<<<dim3(B_), 256, 0, stream>>>(pp, projw, projb, fcw, fcb, outp);
}